// Round 8
// baseline (222.180 us; speedup 1.0000x reference)
//
#include <hip/hip_runtime.h>
#include <math.h>

#define NEGC (-1000.0f)

// ---------- K1Z: blocks [0,136): GEMM  A2 = seg @ W1[:, :512]^T + b1 (128x256),
//                                       B2 = vid @ W1[:, 512:]^T     (2048x256)
//             blocks [136,4760): zero the adj matrix (2176*2176 floats) ----------
__global__ __launch_bounds__(256) void k1z_gemm(
    const float* __restrict__ seg, const float* __restrict__ vid,
    const float* __restrict__ W1, const float* __restrict__ b1,
    float* __restrict__ A2, float* __restrict__ B2, float4* __restrict__ out4)
{
    if (blockIdx.x >= 136) {
        const int i = (blockIdx.x - 136) * 256 + threadIdx.x;
        if (i < 1183744) out4[i] = make_float4(0.f, 0.f, 0.f, 0.f);
        return;
    }
    __shared__ float Xs[32][64];   // [kk][row]
    __shared__ float Ws[32][64];   // [kk][col]
    const int tid = threadIdx.x;
    const int tx = tid & 15, ty = tid >> 4;
    const int lr = tid >> 2;
    const int lk = (tid & 3) * 8;
    const int colBase = (blockIdx.x & 3) * 64;
    const int rowBase = (blockIdx.x >> 2) * 64;
    const bool isSeg = (rowBase < 128);
    const float* __restrict__ X = isSeg ? seg : vid;
    const int xRow = isSeg ? rowBase : (rowBase - 128);
    const int wOff = isSeg ? 0 : 512;

    float acc[4][4] = {};

    for (int k0 = 0; k0 < 512; k0 += 32) {
        const float* xp = X + (size_t)(xRow + lr) * 512 + (k0 + lk);
        const float4 xa = *(const float4*)xp;
        const float4 xb = *(const float4*)(xp + 4);
        const float* wp = W1 + (size_t)(colBase + lr) * 1024 + (wOff + k0 + lk);
        const float4 wa = *(const float4*)wp;
        const float4 wb = *(const float4*)(wp + 4);
        __syncthreads();
        Xs[lk + 0][lr] = xa.x; Xs[lk + 1][lr] = xa.y;
        Xs[lk + 2][lr] = xa.z; Xs[lk + 3][lr] = xa.w;
        Xs[lk + 4][lr] = xb.x; Xs[lk + 5][lr] = xb.y;
        Xs[lk + 6][lr] = xb.z; Xs[lk + 7][lr] = xb.w;
        Ws[lk + 0][lr] = wa.x; Ws[lk + 1][lr] = wa.y;
        Ws[lk + 2][lr] = wa.z; Ws[lk + 3][lr] = wa.w;
        Ws[lk + 4][lr] = wb.x; Ws[lk + 5][lr] = wb.y;
        Ws[lk + 6][lr] = wb.z; Ws[lk + 7][lr] = wb.w;
        __syncthreads();
        #pragma unroll
        for (int kk = 0; kk < 32; ++kk) {
            const float4 a4 = *(const float4*)&Xs[kk][4 * ty];
            const float4 b4 = *(const float4*)&Ws[kk][4 * tx];
            const float* a = (const float*)&a4;
            const float* b = (const float*)&b4;
            #pragma unroll
            for (int i = 0; i < 4; ++i)
                #pragma unroll
                for (int j = 0; j < 4; ++j)
                    acc[i][j] = fmaf(a[i], b[j], acc[i][j]);
        }
    }

    float* __restrict__ outp = (isSeg ? A2 : B2) + (size_t)xRow * 256;
    const int c = colBase + 4 * tx;
    #pragma unroll
    for (int i = 0; i < 4; ++i) {
        float4 v = make_float4(acc[i][0], acc[i][1], acc[i][2], acc[i][3]);
        if (isSeg) {
            v.x += b1[c + 0]; v.y += b1[c + 1]; v.z += b1[c + 2]; v.w += b1[c + 3];
        }
        *(float4*)(outp + (size_t)(4 * ty + i) * 256 + c) = v;
    }
}

// ---------- K2: logitsT[s][n] (for final gather) and lsPK packed [s/2][n][2]:
//   lsPK[s2*256 + 2n + (s&1)] = log_sigmoid(logits[n][s]) ----------
__global__ __launch_bounds__(256) void k2_logits(
    const float* __restrict__ A2, const float* __restrict__ B2,
    const float* __restrict__ W2, const float* __restrict__ b2p,
    float* __restrict__ logitsT, float* __restrict__ lsPK)
{
    __shared__ float As[32][64];   // [kk][n]
    __shared__ float Bs[32][64];   // [kk][s]
    __shared__ float w2s[256];
    const int tid = threadIdx.x;
    const int tx = tid & 15, ty = tid >> 4;
    const int lr = tid >> 2;
    const int lk = (tid & 3) * 8;
    const int nBase = blockIdx.x * 64;
    const int sBase = blockIdx.y * 64;
    w2s[tid] = W2[tid];
    const float b2v = b2p[0];

    float acc[4][4] = {};   // [i:n][j:s]

    for (int k0 = 0; k0 < 256; k0 += 32) {
        const float* ap = A2 + (size_t)(nBase + lr) * 256 + (k0 + lk);
        const float4 aa = *(const float4*)ap;
        const float4 ab = *(const float4*)(ap + 4);
        const float* bp = B2 + (size_t)(sBase + lr) * 256 + (k0 + lk);
        const float4 ba = *(const float4*)bp;
        const float4 bb = *(const float4*)(bp + 4);
        __syncthreads();
        As[lk + 0][lr] = aa.x; As[lk + 1][lr] = aa.y;
        As[lk + 2][lr] = aa.z; As[lk + 3][lr] = aa.w;
        As[lk + 4][lr] = ab.x; As[lk + 5][lr] = ab.y;
        As[lk + 6][lr] = ab.z; As[lk + 7][lr] = ab.w;
        Bs[lk + 0][lr] = ba.x; Bs[lk + 1][lr] = ba.y;
        Bs[lk + 2][lr] = ba.z; Bs[lk + 3][lr] = ba.w;
        Bs[lk + 4][lr] = bb.x; Bs[lk + 5][lr] = bb.y;
        Bs[lk + 6][lr] = bb.z; Bs[lk + 7][lr] = bb.w;
        __syncthreads();
        #pragma unroll
        for (int kk = 0; kk < 32; ++kk) {
            const float w = w2s[k0 + kk];
            const float4 a4 = *(const float4*)&As[kk][4 * ty];
            const float4 b4 = *(const float4*)&Bs[kk][4 * tx];
            const float* a = (const float*)&a4;
            const float* b = (const float*)&b4;
            #pragma unroll
            for (int i = 0; i < 4; ++i)
                #pragma unroll
                for (int j = 0; j < 4; ++j)
                    acc[i][j] = fmaf(fmaxf(a[i] + b[j], 0.0f), w, acc[i][j]);
        }
    }

    const int nb = nBase + 4 * ty;
    const int s0 = sBase + 4 * tx;          // even
    float lsv[4][4];                        // [j:s-offset][i:n-offset]
    #pragma unroll
    for (int j = 0; j < 4; ++j) {
        const int s = s0 + j;
        float4 lg;
        float* lgp = (float*)&lg;
        #pragma unroll
        for (int i = 0; i < 4; ++i) {
            const float x = acc[i][j] + b2v;
            lgp[i] = x;
            lsv[j][i] = fminf(x, 0.0f) - log1pf(expf(-fabsf(x)));
        }
        *(float4*)&logitsT[(size_t)s * 128 + nb] = lg;
    }
    #pragma unroll
    for (int m = 0; m < 2; ++m) {           // two s-pairs
        const size_t base = (size_t)(s0 / 2 + m) * 256 + 2 * nb;
        #pragma unroll
        for (int q = 0; q < 2; ++q) {       // two n-pairs
            float4 v = make_float4(lsv[2 * m][2 * q],     lsv[2 * m + 1][2 * q],
                                   lsv[2 * m][2 * q + 1], lsv[2 * m + 1][2 * q + 1]);
            *(float4*)&lsPK[base + 4 * q] = v;
        }
    }
}

// ---------- K3: 4-wave producer/consumer. Waves 1-3 stage 32KB windows of lsPK
// into a double-buffered LDS ring; wave 0 runs the sequential DP fed by ds_read.
// __syncthreads per window = handoff; producer drain overlaps consumer compute. ----------
__global__ __launch_bounds__(256, 1) void k3_dp(
    const float* __restrict__ lsPK, const float* __restrict__ logitsT,
    float* __restrict__ out)
{
    __shared__ float4 ring[2][2048];       // 2 windows x 32 KB (32 quads x 64 lanes)
    __shared__ unsigned takeW[128 * 65];   // [n][wordIdx], 65-pad -> 2-way only
    const int tid = threadIdx.x;
    const int wave = tid >> 6;
    const int lane = tid & 63;
    const int n0 = 2 * lane, n1 = n0 + 1;
    const float4* __restrict__ ls4 = (const float4*)lsPK;  // ls4[q*64+l] = {even.n0, odd.n0, even.n1, odd.n1}

    // window k holds quads q in [992-32k, 1024-32k), ascending in LDS:
    //   ring[k&1][c*64+lane] = ls4[(992-32k+c)*64+lane], c = 0..31
    auto produce = [&](int k) {            // waves 1..3, chunks c = (wave-1) + 3i
        const size_t base = (size_t)(992 - 32 * k) * 64 + lane;
        const int p = wave - 1;
        float4 t[11];
        #pragma unroll
        for (int i = 0; i < 11; ++i) {
            const int c = p + 3 * i;
            if (c < 32) t[i] = ls4[base + (size_t)c * 64];
        }
        #pragma unroll
        for (int i = 0; i < 11; ++i) {
            const int c = p + 3 * i;
            if (c < 32) ring[k & 1][c * 64 + lane] = t[i];
        }
    };

    float p0 = NEGC, p1 = NEGC;
    unsigned u0 = 2047u - (unsigned)n0;   // s - n0 (head phase)
    unsigned u1 = u0 - 1u;                // s - n1
    unsigned w0 = 0u, w1 = 0u;

    auto core = [&](float lx, float ly, float nx) {
        float c0, c1;
        unsigned long long cc;
        asm volatile(
            "v_add_f32 %[c0], %[lx], %[p1]\n\t"
            "v_add_f32 %[c1], %[ly], %[nx]\n\t"
            "v_cmp_ge_f32 vcc, %[c0], %[p0]\n\t"
            "v_cmp_ge_f32 %[cc], %[c1], %[p1]\n\t"
            "v_addc_co_u32 %[w0], vcc, %[w0], %[w0], vcc\n\t"
            "v_addc_co_u32 %[w1], %[cc], %[w1], %[w1], %[cc]\n\t"
            "v_max_f32 %[p0], %[c0], %[p0]\n\t"
            "v_max_f32 %[p1], %[c1], %[p1]\n\t"
            : [p0]"+v"(p0), [p1]"+v"(p1), [w0]"+v"(w0), [w1]"+v"(w1),
              [c0]"=&v"(c0), [c1]"=&v"(c1), [cc]"=&s"(cc)
            : [lx]"v"(lx), [ly]"v"(ly), [nx]"v"(nx)
            : "vcc");
    };

    auto stepF = [&](float lx, float ly) { // in-band: no range masking
        float nxt1 = __int_as_float(__builtin_amdgcn_update_dpp(
            0, __float_as_int(p0), 0x130 /*WAVE_SHL1*/, 0xf, 0xf, true));
        core(lx, ly, nxt1);
    };
    auto stepM = [&](float lx, float ly) { // masked (head/tail)
        float nxt1 = __int_as_float(__builtin_amdgcn_update_dpp(
            0, __float_as_int(p0), 0x130, 0xf, 0xf, true));
        core(lx, ly, nxt1);
        p0 = (u0 <= 1920u) ? p0 : NEGC;   // 0 <= s-n <= 1920 (wrap covers s<n)
        p1 = (u1 <= 1920u) ? p1 : NEGC;
        --u0; --u1;
    };

    float4 C0, C1, C2, C3, N0, N1, N2, N3;   // register double-buffer across sub-groups
    int wIdx = 63;
#define RD(B, OFF) B = rb[(OFF) * 64 + lane];
#define CONS4(STEP, Ba, Bb, Bc, Bd) { \
    STEP(Ba.y, Ba.w); STEP(Ba.x, Ba.z); STEP(Bb.y, Bb.w); STEP(Bb.x, Bb.z); \
    STEP(Bc.y, Bc.w); STEP(Bc.x, Bc.z); STEP(Bd.y, Bd.w); STEP(Bd.x, Bd.z); }
#define FLUSH { takeW[n0 * 65 + wIdx] = w0; takeW[n1 * 65 + wIdx] = w1; \
                w0 = 0u; w1 = 0u; --wIdx; }
#define WINDOW(STEP) { \
    RD(C0,31) RD(C1,30) RD(C2,29) RD(C3,28) \
    RD(N0,27) RD(N1,26) RD(N2,25) RD(N3,24) CONS4(STEP,C0,C1,C2,C3) \
    RD(C0,23) RD(C1,22) RD(C2,21) RD(C3,20) CONS4(STEP,N0,N1,N2,N3) \
    RD(N0,19) RD(N1,18) RD(N2,17) RD(N3,16) CONS4(STEP,C0,C1,C2,C3) \
    RD(C0,15) RD(C1,14) RD(C2,13) RD(C3,12) CONS4(STEP,N0,N1,N2,N3) FLUSH \
    RD(N0,11) RD(N1,10) RD(N2, 9) RD(N3, 8) CONS4(STEP,C0,C1,C2,C3) \
    RD(C0, 7) RD(C1, 6) RD(C2, 5) RD(C3, 4) CONS4(STEP,N0,N1,N2,N3) \
    RD(N0, 3) RD(N1, 2) RD(N2, 1) RD(N3, 0) CONS4(STEP,C0,C1,C2,C3) \
    CONS4(STEP,N0,N1,N2,N3) FLUSH }

    if (wave > 0) produce(0);
    __syncthreads();

    for (int k = 0; k < 32; ++k) {
        if (wave > 0) {
            if (k + 1 < 32) produce(k + 1);
        } else {
            const float4* rb = &ring[k & 1][0];
            if (k < 2) {                    // head: s 2047..1920, masked
                WINDOW(stepM)
            } else if (k < 30) {            // mid: in-band
                WINDOW(stepF)
            } else {                        // tail: s 127..0, masked
                if (k == 30) { u0 = (unsigned)(127 - n0); u1 = u0 - 1u; }
                WINDOW(stepM)
            }
        }
        __syncthreads();                    // handoff: ring[(k+1)&1] now complete
    }
#undef WINDOW
#undef FLUSH
#undef CONS4
#undef RD

    if (wave != 0) return;                  // no barriers beyond this point

    // wave-parallel walk: lane holds word 'lane' of row n; ballot -> first set bit.
    // (takeW written by wave 0 itself; per-wave DS ops complete in order.)
    int a0r = 0, a1r = 0, pos = 0;
    for (int n = 0; n < 128; ++n) {
        unsigned w = takeW[n * 65 + lane];
        const int wi0 = pos >> 5;
        if (lane < wi0) w = 0u;
        else if (lane == wi0) w &= (0xFFFFFFFFu << (pos & 31));
        const unsigned long long m = __ballot(w != 0u);
        if (m == 0ull) break;               // uniform
        const int fl = __builtin_ctzll(m);
        const unsigned fw = (unsigned)__builtin_amdgcn_readlane((int)w, fl);
        const int s = fl * 32 + __builtin_ctz(fw);  // wave-uniform
        if (n == n0) a0r = s;
        if (n == n1) a1r = s;
        pos = s + 1;
    }

    out[(size_t)(2048 + n0) * 2176 + a0r] = 1.0f;
    out[(size_t)(2048 + n1) * 2176 + a1r] = 1.0f;
    float sum = logitsT[(size_t)a0r * 128 + n0] + logitsT[(size_t)a1r * 128 + n1];
    #pragma unroll
    for (int off = 32; off >= 1; off >>= 1) sum += __shfl_down(sum, off);
    if (lane == 0) out[(size_t)2176 * 2176] = sum * (1.0f / 128.0f);
}

extern "C" void kernel_launch(void* const* d_in, const int* in_sizes, int n_in,
                              void* d_out, int out_size, void* d_ws, size_t ws_size,
                              hipStream_t stream)
{
    const float* seg = (const float*)d_in[0];   // [128][512]
    const float* vid = (const float*)d_in[1];   // [2048][512]
    const float* W1  = (const float*)d_in[2];   // [256][1024]
    const float* b1  = (const float*)d_in[3];   // [256]
    const float* W2  = (const float*)d_in[4];   // [256]
    const float* b2  = (const float*)d_in[5];   // [1]
    float* out = (float*)d_out;
    float* ws  = (float*)d_ws;

    float* A2      = ws;             // 128*256
    float* B2      = ws + 32768;     // 2048*256
    float* logitsT = ws + 557056;    // 2048*128, [s][n]
    float* lsPK    = ws + 819200;    // 2048*128 packed [s/2][n][2]

    k1z_gemm<<<dim3(4760), dim3(256), 0, stream>>>(seg, vid, W1, b1, A2, B2, (float4*)out);
    k2_logits<<<dim3(2, 32), dim3(256), 0, stream>>>(A2, B2, W2, b2, logitsT, lsPK);
    k3_dp<<<dim3(1), dim3(256), 0, stream>>>(lsPK, logitsT, out);
}